// Round 1
// baseline (509.692 us; speedup 1.0000x reference)
//
#include <hip/hip_runtime.h>
#include <stdint.h>

typedef __attribute__((ext_vector_type(8))) short short8;
typedef __attribute__((ext_vector_type(4))) float floatx4;

#define SEQQ 256
#define SEQK 256
#define HD   64
#define KSTR 72    // K LDS row stride (bf16 units), 144 B -> even bank tiling for b128
#define VTSTR 264  // Vt LDS row stride (bf16 units), 528 B
#define PSTR 40    // P scratch row stride (bf16 units), 80 B

__device__ __forceinline__ unsigned short f2b(float x) {
    union { float f; uint32_t u; } v; v.f = x;
    return (unsigned short)((v.u + 0x7FFFu + ((v.u >> 16) & 1u)) >> 16);  // RNE
}
__device__ __forceinline__ uint32_t pack2(float a, float b) {
    return (uint32_t)f2b(a) | ((uint32_t)f2b(b) << 16);
}

__global__ __launch_bounds__(256) void attn_fused(
    const float* __restrict__ Qg, const float* __restrict__ Kg,
    const float* __restrict__ Vg, const int* __restrict__ Lg,
    const float* __restrict__ WMg, float* __restrict__ Og)
{
    // K tile (bf16) lives here first, then V^T (bf16) overwrites it after a barrier.
    __shared__ __align__(16) unsigned short ldsKV[SEQK * KSTR];        // 36864 B (Vt needs 64*264=16896 shorts)
    __shared__ __align__(16) unsigned short ldsP[4 * 2 * 16 * PSTR];   // wave-private, double-buffered P scratch

    const int tid   = threadIdx.x;
    const int lane  = tid & 63;
    const int wave  = tid >> 6;
    const int row16 = lane & 15;
    const int quad  = lane >> 4;

    const int bidx  = blockIdx.x;
    const int batch = bidx >> 2;
    const int qb    = bidx & 3;
    const int q0    = qb * 64 + wave * 16;   // this wave's q-row base within the batch

    const float* qptr = Qg + (size_t)batch * SEQQ * HD;
    const float* kptr = Kg + (size_t)batch * SEQK * HD;
    const float* vptr = Vg + (size_t)batch * SEQK * HD;
    const float* wptr = WMg + (size_t)((batch >> 3) & 63) * SEQQ * SEQK;
    const int L = Lg[batch];

    // ---- stage K -> LDS bf16 [kv][d] ----
    #pragma unroll
    for (int it = 0; it < 32; ++it) {
        int pe  = it * 256 + tid;       // 8192 float2's
        int kvr = pe >> 5;              // kv row (32 pairs per row)
        int pi  = pe & 31;
        const float2 f = *(const float2*)(kptr + kvr * HD + pi * 2);
        *(uint32_t*)&ldsKV[kvr * KSTR + pi * 2] = pack2(f.x, f.y);
    }

    // ---- Q fragments (A-layout: A[m=lane&15][k=quad*8+j]) ----
    short8 qf0, qf1;
    {
        const float* qr = qptr + (q0 + row16) * HD + quad * 8;
        float4 a = *(const float4*)(qr);
        float4 b = *(const float4*)(qr + 4);
        float4 c = *(const float4*)(qr + 32);
        float4 d = *(const float4*)(qr + 36);
        qf0 = (short8){ (short)f2b(a.x),(short)f2b(a.y),(short)f2b(a.z),(short)f2b(a.w),
                        (short)f2b(b.x),(short)f2b(b.y),(short)f2b(b.z),(short)f2b(b.w) };
        qf1 = (short8){ (short)f2b(c.x),(short)f2b(c.y),(short)f2b(c.z),(short)f2b(c.w),
                        (short)f2b(d.x),(short)f2b(d.y),(short)f2b(d.z),(short)f2b(d.w) };
    }

    __syncthreads();

    // ---- S = Q K^T  (16 kv-tiles, K=64 in 2 MFMA steps) ----
    floatx4 acc[16];
    #pragma unroll
    for (int j = 0; j < 16; ++j) acc[j] = (floatx4){0.f, 0.f, 0.f, 0.f};
    #pragma unroll
    for (int j = 0; j < 16; ++j) {
        const unsigned short* kb = &ldsKV[(j * 16 + row16) * KSTR + quad * 8];
        short8 kf0 = *(const short8*)kb;
        short8 kf1 = *(const short8*)(kb + 32);
        acc[j] = __builtin_amdgcn_mfma_f32_16x16x32_bf16(qf0, kf0, acc[j], 0, 0, 0);
        acc[j] = __builtin_amdgcn_mfma_f32_16x16x32_bf16(qf1, kf1, acc[j], 0, 0, 0);
    }

    // ---- masked softmax (rows in C-layout: q = q0 + quad*4 + r, kv = 16j + row16) ----
    float inv[4];
    #pragma unroll
    for (int r = 0; r < 4; ++r) {
        const int qrow = q0 + quad * 4 + r;
        const float* wr = wptr + qrow * SEQK + row16;
        float mx = -3.0e38f;
        #pragma unroll
        for (int j = 0; j < 16; ++j) {
            float s = acc[j][r] * 0.125f + wr[16 * j];
            s = (16 * j + row16 < L) ? s : -1.0e6f;   // replace, not add (matches reference)
            acc[j][r] = s;
            mx = fmaxf(mx, s);
        }
        #pragma unroll
        for (int o = 1; o < 16; o <<= 1) mx = fmaxf(mx, __shfl_xor(mx, o, 64));
        float sm = 0.f;
        #pragma unroll
        for (int j = 0; j < 16; ++j) {
            float e = exp2f((acc[j][r] - mx) * 1.44269504088896f);
            acc[j][r] = e;
            sm += e;
        }
        #pragma unroll
        for (int o = 1; o < 16; o <<= 1) sm += __shfl_xor(sm, o, 64);
        inv[r] = __builtin_amdgcn_rcpf(sm);
    }

    __syncthreads();   // all waves done reading K

    // ---- stage V^T -> LDS bf16 [d][kv] over the K buffer ----
    #pragma unroll 4
    for (int it = 0; it < 16; ++it) {
        int p4 = it * 256 + tid;        // 4096 groups of 4 kv
        int d  = p4 & 63;
        int k4 = p4 >> 6;
        int kv = k4 * 4;
        float v0 = vptr[(kv + 0) * HD + d];
        float v1 = vptr[(kv + 1) * HD + d];
        float v2 = vptr[(kv + 2) * HD + d];
        float v3 = vptr[(kv + 3) * HD + d];
        uint2 pk; pk.x = pack2(v0, v1); pk.y = pack2(v2, v3);
        *(uint2*)&ldsKV[d * VTSTR + kv] = pk;
    }

    __syncthreads();

    // ---- O = P V : per 32-kv chunk, C-layout -> LDS -> A-layout round trip ----
    floatx4 oacc[4];
    #pragma unroll
    for (int t = 0; t < 4; ++t) oacc[t] = (floatx4){0.f, 0.f, 0.f, 0.f};
    unsigned short* psbase = &ldsP[wave * 2 * 16 * PSTR];
    #pragma unroll
    for (int c = 0; c < 8; ++c) {
        unsigned short* ps = psbase + (c & 1) * 16 * PSTR;
        #pragma unroll
        for (int r = 0; r < 4; ++r) {
            const int prow = quad * 4 + r;
            ps[prow * PSTR + row16]      = f2b(acc[2 * c    ][r] * inv[r]);
            ps[prow * PSTR + 16 + row16] = f2b(acc[2 * c + 1][r] * inv[r]);
        }
        __asm__ __volatile__("" ::: "memory");                 // no compiler reorder across the round trip
        __builtin_amdgcn_s_waitcnt(0xC07F);                    // lgkmcnt(0): writes drained (wave-synchronous read)
        short8 pf = *(const short8*)&ps[row16 * PSTR + quad * 8];
        #pragma unroll
        for (int t = 0; t < 4; ++t) {
            short8 vf = *(const short8*)&ldsKV[(t * 16 + row16) * VTSTR + c * 32 + quad * 8];
            oacc[t] = __builtin_amdgcn_mfma_f32_16x16x32_bf16(pf, vf, oacc[t], 0, 0, 0);
        }
    }

    // ---- store O (C-layout: row = q0+quad*4+r, col = t*16+row16) ----
    float* op = Og + (size_t)batch * SEQQ * HD;
    #pragma unroll
    for (int t = 0; t < 4; ++t) {
        #pragma unroll
        for (int r = 0; r < 4; ++r) {
            op[(q0 + quad * 4 + r) * HD + t * 16 + row16] = oacc[t][r];
        }
    }
}

extern "C" void kernel_launch(void* const* d_in, const int* in_sizes, int n_in,
                              void* d_out, int out_size, void* d_ws, size_t ws_size,
                              hipStream_t stream) {
    const float* Qg = (const float*)d_in[0];
    const float* Kg = (const float*)d_in[1];
    const float* Vg = (const float*)d_in[2];
    const int*   Lg = (const int*)d_in[3];
    const float* Wm = (const float*)d_in[4];
    float* Og = (float*)d_out;

    const int nbatch = in_sizes[3];          // 2048
    dim3 grid(nbatch * 4), block(256);
    hipLaunchKernelGGL(attn_fused, grid, block, 0, stream, Qg, Kg, Vg, Lg, Wm, Og);
}

// Round 2
// 472.611 us; speedup vs baseline: 1.0785x; 1.0785x over previous
//
#include <hip/hip_runtime.h>
#include <stdint.h>

typedef __attribute__((ext_vector_type(8))) short short8;
typedef __attribute__((ext_vector_type(4))) float floatx4;

#define SEQQ 256
#define SEQK 256
#define HD   64
#define KSTR 72    // K LDS row stride (bf16): 144 B/row -> 16B-aligned b128 reads, min-cycle banks
#define VTSTR 264  // Vt LDS row stride (bf16): 528 B/row -> 16B-aligned b128 reads
#define PSTR 40    // P scratch row stride (bf16): 80 B/row -> 16B-aligned b128 reads

// round-half-up bf16 pair pack: 2x v_add_u32 + 1x v_perm_b32 (vs ~12 ops software RNE)
__device__ __forceinline__ uint32_t rpack2(float a, float b) {
    uint32_t ua = __builtin_bit_cast(uint32_t, a) + 0x8000u;
    uint32_t ub = __builtin_bit_cast(uint32_t, b) + 0x8000u;
    return __builtin_amdgcn_perm(ub, ua, 0x07060302u);  // [a.hi16 | b.hi16<<16]
}
__device__ __forceinline__ unsigned short f2b(float x) {
    return (unsigned short)((__builtin_bit_cast(uint32_t, x) + 0x8000u) >> 16);
}
__device__ __forceinline__ float b2f(unsigned short b) {
    return __builtin_bit_cast(float, ((uint32_t)b) << 16);
}

// WM fp32 -> bf16 preconvert (runs every launch; d_ws is re-poisoned by harness)
__global__ __launch_bounds__(256) void wm_convert(const float* __restrict__ wm,
                                                  unsigned short* __restrict__ out) {
    int i = (blockIdx.x * 256 + threadIdx.x) * 8;
    float4 a = *(const float4*)(wm + i);
    float4 b = *(const float4*)(wm + i + 4);
    uint4 o;
    o.x = rpack2(a.x, a.y); o.y = rpack2(a.z, a.w);
    o.z = rpack2(b.x, b.y); o.w = rpack2(b.z, b.w);
    *(uint4*)(out + i) = o;
}

template <bool WMBF16>
__global__ __launch_bounds__(256) void attn_fused(
    const float* __restrict__ Qg, const float* __restrict__ Kg,
    const float* __restrict__ Vg, const int* __restrict__ Lg,
    const void* __restrict__ WMg, float* __restrict__ Og)
{
    __shared__ __align__(16) unsigned short ldsKV[SEQK * KSTR];        // K tile, then Vt overlays
    __shared__ __align__(16) unsigned short ldsP[4 * 2 * 16 * PSTR];   // wave-private dbuf P scratch

    const int tid   = threadIdx.x;
    const int lane  = tid & 63;
    const int wave  = tid >> 6;
    const int row16 = lane & 15;
    const int quad  = lane >> 4;

    const int bidx  = blockIdx.x;
    const int batch = bidx >> 2;
    const int qb    = bidx & 3;
    const int q0    = qb * 64 + wave * 16;

    const float* qptr = Qg + (size_t)batch * SEQQ * HD;
    const float* kptr = Kg + (size_t)batch * SEQK * HD;
    const float* vptr = Vg + (size_t)batch * SEQK * HD;
    const size_t wmoff = (size_t)((batch >> 3) & 63) * SEQQ * SEQK;
    const int L = Lg[batch];

    // ---- stage K -> LDS bf16 [kv][d], float4 loads ----
    #pragma unroll
    for (int it = 0; it < 16; ++it) {
        int pe  = it * 256 + tid;       // 4096 float4's
        int kvr = pe >> 4;
        int pi  = pe & 15;
        const float4 f = *(const float4*)(kptr + kvr * HD + pi * 4);
        uint2 pk; pk.x = rpack2(f.x, f.y); pk.y = rpack2(f.z, f.w);
        *(uint2*)&ldsKV[kvr * KSTR + pi * 4] = pk;
    }

    // ---- Q fragments (A-layout: A[m=lane&15][k=quad*8+j]) ----
    short8 qf0, qf1;
    {
        const float* qr = qptr + (q0 + row16) * HD + quad * 8;
        float4 a = *(const float4*)(qr);
        float4 b = *(const float4*)(qr + 4);
        float4 c = *(const float4*)(qr + 32);
        float4 d = *(const float4*)(qr + 36);
        union { short8 s; uint32_t u[4]; } t0, t1;
        t0.u[0] = rpack2(a.x, a.y); t0.u[1] = rpack2(a.z, a.w);
        t0.u[2] = rpack2(b.x, b.y); t0.u[3] = rpack2(b.z, b.w);
        t1.u[0] = rpack2(c.x, c.y); t1.u[1] = rpack2(c.z, c.w);
        t1.u[2] = rpack2(d.x, d.y); t1.u[3] = rpack2(d.z, d.w);
        qf0 = t0.s; qf1 = t1.s;
    }

    __syncthreads();

    // ---- S = Q K^T ----
    floatx4 acc[16];
    #pragma unroll
    for (int j = 0; j < 16; ++j) acc[j] = (floatx4){0.f, 0.f, 0.f, 0.f};
    #pragma unroll
    for (int j = 0; j < 16; ++j) {
        const unsigned short* kb = &ldsKV[(j * 16 + row16) * KSTR + quad * 8];
        short8 kf0 = *(const short8*)kb;
        short8 kf1 = *(const short8*)(kb + 32);
        acc[j] = __builtin_amdgcn_mfma_f32_16x16x32_bf16(qf0, kf0, acc[j], 0, 0, 0);
        acc[j] = __builtin_amdgcn_mfma_f32_16x16x32_bf16(qf1, kf1, acc[j], 0, 0, 0);
    }

    __syncthreads();   // all waves done reading K; Vt may overwrite

    // ---- stage V^T -> LDS bf16 [d][kv] (loads overlap the softmax below) ----
    #pragma unroll 4
    for (int it = 0; it < 16; ++it) {
        int p4 = it * 256 + tid;
        int d  = p4 & 63;
        int kv = (p4 >> 6) * 4;
        float v0 = vptr[(kv + 0) * HD + d];
        float v1 = vptr[(kv + 1) * HD + d];
        float v2 = vptr[(kv + 2) * HD + d];
        float v3 = vptr[(kv + 3) * HD + d];
        uint2 pk; pk.x = rpack2(v0, v1); pk.y = rpack2(v2, v3);
        *(uint2*)&ldsKV[d * VTSTR + kv] = pk;
    }

    // ---- masked softmax (C-layout: q = q0+quad*4+r, kv = 16j+row16) ----
    float inv[4];
    #pragma unroll
    for (int r = 0; r < 4; ++r) {
        const int qrow = q0 + quad * 4 + r;
        float wv[16];
        if (WMBF16) {
            const unsigned short* wr = (const unsigned short*)WMg + wmoff + qrow * SEQK + row16;
            #pragma unroll
            for (int j = 0; j < 16; ++j) wv[j] = b2f(wr[16 * j]);
        } else {
            const float* wr = (const float*)WMg + wmoff + qrow * SEQK + row16;
            #pragma unroll
            for (int j = 0; j < 16; ++j) wv[j] = wr[16 * j];
        }
        float mx = -3.0e38f;
        #pragma unroll
        for (int j = 0; j < 16; ++j) {
            float s = acc[j][r] * 0.125f + wv[j];
            s = (16 * j + row16 < L) ? s : -1.0e6f;   // replace (matches reference)
            acc[j][r] = s;
            mx = fmaxf(mx, s);
        }
        #pragma unroll
        for (int o = 1; o < 16; o <<= 1) mx = fmaxf(mx, __shfl_xor(mx, o, 64));
        float sm = 0.f;
        #pragma unroll
        for (int j = 0; j < 16; ++j) {
            float e = exp2f((acc[j][r] - mx) * 1.44269504088896f);
            acc[j][r] = e;
            sm += e;
        }
        #pragma unroll
        for (int o = 1; o < 16; o <<= 1) sm += __shfl_xor(sm, o, 64);
        inv[r] = __builtin_amdgcn_rcpf(sm);
    }

    __syncthreads();   // Vt fully staged & visible

    // ---- O = P V : per 32-kv chunk, C-layout -> LDS -> A-layout round trip ----
    floatx4 oacc[4];
    #pragma unroll
    for (int t = 0; t < 4; ++t) oacc[t] = (floatx4){0.f, 0.f, 0.f, 0.f};
    unsigned short* psbase = &ldsP[wave * 2 * 16 * PSTR];
    #pragma unroll
    for (int c = 0; c < 8; ++c) {
        unsigned short* ps = psbase + (c & 1) * 16 * PSTR;
        #pragma unroll
        for (int r = 0; r < 4; ++r) {
            const int prow = quad * 4 + r;
            ps[prow * PSTR + row16]      = f2b(acc[2 * c    ][r] * inv[r]);
            ps[prow * PSTR + 16 + row16] = f2b(acc[2 * c + 1][r] * inv[r]);
        }
        __asm__ __volatile__("" ::: "memory");
        __builtin_amdgcn_s_waitcnt(0xC07F);            // lgkmcnt(0), wave-synchronous round trip
        short8 pf = *(const short8*)&ps[row16 * PSTR + quad * 8];
        #pragma unroll
        for (int t = 0; t < 4; ++t) {
            short8 vf = *(const short8*)&ldsKV[(t * 16 + row16) * VTSTR + c * 32 + quad * 8];
            oacc[t] = __builtin_amdgcn_mfma_f32_16x16x32_bf16(pf, vf, oacc[t], 0, 0, 0);
        }
    }

    // ---- store O ----
    float* op = Og + (size_t)batch * SEQQ * HD;
    #pragma unroll
    for (int t = 0; t < 4; ++t) {
        #pragma unroll
        for (int r = 0; r < 4; ++r) {
            op[(q0 + quad * 4 + r) * HD + t * 16 + row16] = oacc[t][r];
        }
    }
}

extern "C" void kernel_launch(void* const* d_in, const int* in_sizes, int n_in,
                              void* d_out, int out_size, void* d_ws, size_t ws_size,
                              hipStream_t stream) {
    const float* Qg = (const float*)d_in[0];
    const float* Kg = (const float*)d_in[1];
    const float* Vg = (const float*)d_in[2];
    const int*   Lg = (const int*)d_in[3];
    const float* Wm = (const float*)d_in[4];
    float* Og = (float*)d_out;

    const int nbatch = in_sizes[3];          // 2048
    const int wm_elems = in_sizes[4];        // 64*256*256
    dim3 block(256);

    if ((size_t)wm_elems * sizeof(unsigned short) <= ws_size) {
        unsigned short* wmb = (unsigned short*)d_ws;
        hipLaunchKernelGGL(wm_convert, dim3(wm_elems / 2048), block, 0, stream, Wm, wmb);
        hipLaunchKernelGGL((attn_fused<true>), dim3(nbatch * 4), block, 0, stream,
                           Qg, Kg, Vg, Lg, (const void*)wmb, Og);
    } else {
        hipLaunchKernelGGL((attn_fused<false>), dim3(nbatch * 4), block, 0, stream,
                           Qg, Kg, Vg, Lg, (const void*)Wm, Og);
    }
}